// Round 11
// baseline (447.029 us; speedup 1.0000x reference)
//
#include <hip/hip_runtime.h>

// GCN 4-layer forward on MI355X.
// Reference: h' = relu( norm_dst * segsum_{dst}( ((h*norm_src) @ W)[src] ) + b )
//
// Round 11:
//  - Gather: XCD-pinned column groups. blockIdx&7 -> column group g (16 cols
//    for D=128, 8 for D=64); round-robin block->XCD map pins group g to XCD g,
//    whose 3.2MB x-slice stays resident in its private 4MB L2 (r2 evidence:
//    132MB FETCH for a 25.6MB buffer = every XCD pulling all of x). Each lane
//    owns 4 cols end-to-end: no shfl reduce at all.
//  - Fused deg+gemm0 reverted to r9 exact structure (256 dedicated atomic
//    blocks first; r10's distributed variant delayed GEMM starts, +11us).

namespace {

constexpr int NN = 50000;      // nodes
constexpr int NE = 600000;     // edges
constexpr int SCAN_BLK = 256;
constexpr int NBLK = (NN + SCAN_BLK - 1) / SCAN_BLK;  // 196
constexpr int DEG_BLOCKS = 256;
constexpr int GEMM_TILES = (NN + 63) / 64;            // 782

__global__ void norm_kernel(const int* __restrict__ dego, const int* __restrict__ degi,
                            float* __restrict__ ns, float* __restrict__ nd) {
  int i = blockIdx.x * blockDim.x + threadIdx.x;
  if (i < NN) {
    int a = dego[i]; if (a < 1) a = 1;
    int b = degi[i]; if (b < 1) b = 1;
    ns[i] = 1.0f / sqrtf((float)a);
    nd[i] = 1.0f / sqrtf((float)b);
  }
}

// --- 3-phase scan of degi[NN] -> rowptr[NN+1] (exclusive) ---

__global__ __launch_bounds__(SCAN_BLK) void scan_phase1(const int* __restrict__ deg,
                                                        int* __restrict__ bsum) {
  __shared__ int ws[SCAN_BLK / 64];
  int i = blockIdx.x * SCAN_BLK + threadIdx.x;
  int v = (i < NN) ? deg[i] : 0;
#pragma unroll
  for (int off = 32; off; off >>= 1) v += __shfl_down(v, off, 64);
  int lane = threadIdx.x & 63, w = threadIdx.x >> 6;
  if (lane == 0) ws[w] = v;
  __syncthreads();
  if (threadIdx.x == 0) {
    int s = 0;
#pragma unroll
    for (int k = 0; k < SCAN_BLK / 64; ++k) s += ws[k];
    bsum[blockIdx.x] = s;
  }
}

__global__ __launch_bounds__(256) void scan_phase2(const int* __restrict__ bsum,
                                                   int* __restrict__ bpre,
                                                   int* __restrict__ rowptr) {
  __shared__ int s[256];
  int t = threadIdx.x;
  int v = (t < NBLK) ? bsum[t] : 0;
  s[t] = v;
  __syncthreads();
  for (int off = 1; off < 256; off <<= 1) {
    int u = (t >= off) ? s[t - off] : 0;
    __syncthreads();
    s[t] += u;
    __syncthreads();
  }
  if (t < NBLK) bpre[t] = s[t] - v;  // exclusive
  if (t == 255) rowptr[NN] = s[255]; // total == NE
}

__global__ __launch_bounds__(SCAN_BLK) void scan_phase3(const int* __restrict__ deg,
                                                        const int* __restrict__ bpre,
                                                        int* __restrict__ rowptr) {
  __shared__ int s[SCAN_BLK];
  int t = threadIdx.x;
  int i = blockIdx.x * SCAN_BLK + t;
  int v = (i < NN) ? deg[i] : 0;
  s[t] = v;
  __syncthreads();
  for (int off = 1; off < SCAN_BLK; off <<= 1) {
    int u = (t >= off) ? s[t - off] : 0;
    __syncthreads();
    s[t] += u;
    __syncthreads();
  }
  if (i < NN) rowptr[i] = bpre[blockIdx.x] + s[t] - v;
}

// atomic-free CSR fill using le slots recorded during counting
__global__ void scatter_kernel(const int* __restrict__ src, const int* __restrict__ dst,
                               const int* __restrict__ le, const int* __restrict__ rowptr,
                               int* __restrict__ col) {
  int e = blockIdx.x * blockDim.x + threadIdx.x;
  if (e < NE) col[rowptr[dst[e]] + le[e]] = src[e];
}

// ---- GEMM tile body ----
// x[row][j] = sum_k (opt ns[row] *) h[row][k] * W[k][j]    K = 128
// 64 rows x DO cols per tile; 256 threads = 16rq x 16cq, 4x4 per col-half.
// hs[64][132] row-major (coalesced staging, padded: conflict-free b128);
// wl[128][64] per half (2-way broadcast reads, free). 66.5KB LDS, 2 blk/CU.
template <int DO, bool USE_NS>
__device__ void gemm_body(const float* __restrict__ h, const float* __restrict__ W,
                          const float* __restrict__ ns, float* __restrict__ x,
                          int row0) {
  constexpr int CH = DO / 64;
  __shared__ __align__(16) float hs[64 * 132];  // 33.8 KB
  __shared__ __align__(16) float wl[128 * 64];  // 32 KB
  const int tid = threadIdx.x;

  // stage hs (optionally ns-folded): coalesced (32 lanes x float4 per row)
#pragma unroll
  for (int it = 0; it < 8; ++it) {
    int flat = it * 256 + tid;
    int row = flat >> 5;
    int c = flat & 31;
    int grow = row0 + row;
    float4 hv = make_float4(0.f, 0.f, 0.f, 0.f);
    float sc = 0.f;
    if (grow < NN) {
      hv = *reinterpret_cast<const float4*>(&h[(size_t)grow * 128 + c * 4]);
      sc = USE_NS ? ns[grow] : 1.0f;
    }
    float* d = &hs[row * 132 + c * 4];
    d[0] = hv.x * sc; d[1] = hv.y * sc; d[2] = hv.z * sc; d[3] = hv.w * sc;
  }

  const int rq = tid >> 4;
  const int cq = tid & 15;

  for (int ch = 0; ch < CH; ++ch) {
    __syncthreads();  // ch=0: hs ready; ch>0: wl no longer being read
#pragma unroll
    for (int it = 0; it < 8; ++it) {
      int flat = it * 256 + tid;
      int k = flat >> 4;
      int c4 = flat & 15;
      *reinterpret_cast<float4*>(&wl[k * 64 + c4 * 4]) =
          *reinterpret_cast<const float4*>(&W[k * DO + ch * 64 + c4 * 4]);
    }
    __syncthreads();

    float acc[4][4] = {{0.f}};
#pragma unroll 4
    for (int k4 = 0; k4 < 32; ++k4) {
      float hv[4][4], wv[4][4];
#pragma unroll
      for (int i = 0; i < 4; ++i) {
        float4 t = *reinterpret_cast<const float4*>(&hs[(rq * 4 + i) * 132 + k4 * 4]);
        hv[i][0] = t.x; hv[i][1] = t.y; hv[i][2] = t.z; hv[i][3] = t.w;
      }
#pragma unroll
      for (int kk = 0; kk < 4; ++kk) {
        float4 t = *reinterpret_cast<const float4*>(&wl[(k4 * 4 + kk) * 64 + cq * 4]);
        wv[kk][0] = t.x; wv[kk][1] = t.y; wv[kk][2] = t.z; wv[kk][3] = t.w;
      }
#pragma unroll
      for (int i = 0; i < 4; ++i)
#pragma unroll
        for (int kk = 0; kk < 4; ++kk)
#pragma unroll
          for (int j = 0; j < 4; ++j)
            acc[i][j] = fmaf(hv[i][kk], wv[kk][j], acc[i][j]);
    }

#pragma unroll
    for (int i = 0; i < 4; ++i) {
      int row = row0 + rq * 4 + i;
      if (row < NN) {
        *reinterpret_cast<float4*>(&x[(size_t)row * DO + ch * 64 + cq * 4]) =
            make_float4(acc[i][0], acc[i][1], acc[i][2], acc[i][3]);
      }
    }
  }
}

// Fused (r9 structure): blocks [0,DEG_BLOCKS) run degree counting + le
// (grid-stride, fire atomics from t=0); blocks [DEG_BLOCKS,...) run layer-0
// GEMM tiles (x0 = h0 @ W0, unscaled; ns folded into gather-0).
__global__ __launch_bounds__(256, 2) void gemm0_deg_kernel(
    const float* __restrict__ h, const float* __restrict__ W,
    float* __restrict__ x,
    const int* __restrict__ src, const int* __restrict__ dst,
    int* __restrict__ dego, int* __restrict__ degi, int* __restrict__ le) {
  if (blockIdx.x < DEG_BLOCKS) {
    const int stride = DEG_BLOCKS * 256;
    for (int e = blockIdx.x * 256 + threadIdx.x; e < NE; e += stride) {
      atomicAdd(&dego[src[e]], 1);
      le[e] = atomicAdd(&degi[dst[e]], 1);
    }
    return;
  }
  gemm_body<128, false>(h, W, nullptr, x, (blockIdx.x - DEG_BLOCKS) * 64);
}

template <int DO>
__global__ __launch_bounds__(256, 2) void gemm_ns(const float* __restrict__ h,
                                                  const float* __restrict__ W,
                                                  const float* __restrict__ ns,
                                                  float* __restrict__ x) {
  gemm_body<DO, true>(h, W, ns, x, blockIdx.x * 64);
}

// XCD-pinned column-group gather.
// g = blockIdx&7 -> column group (GC = D/8 cols). With the round-robin
// block->XCD map, all blocks of group g land on XCD g, whose x column-slice
// (50000 * GC * 4B <= 3.2MB) stays resident in that XCD's private 4MB L2.
// Lane layout: nsub = lane/CPL node within the wave's batch, cidx = lane%CPL
// float4-slot; each lane owns its 4 columns fully (no cross-lane reduce).
// Wave-strided over nodes; 4 edges in flight per node (unroll).
template <int D, bool RELU, bool NSRC>
__global__ __launch_bounds__(256) void gather_kernel(const float* __restrict__ x,
                                                     const int* __restrict__ rowptr,
                                                     const int* __restrict__ col,
                                                     const float* __restrict__ nd,
                                                     const float* __restrict__ b,
                                                     const float* __restrict__ nsv,
                                                     float* __restrict__ out) {
  constexpr int GC = D / 8;      // cols per group: 16 (D=128) or 8 (D=64)
  constexpr int CPL = GC / 4;    // float4 slots per node: 4 or 2
  constexpr int NPW = 64 / CPL;  // nodes per wave batch: 16 or 32
  const int g = blockIdx.x & 7;
  const int lane = threadIdx.x & 63;
  const int w = threadIdx.x >> 6;
  const int nsub = lane / CPL;
  const int cidx = lane % CPL;
  const int c0 = g * GC + cidx * 4;
  const int wavesPerGroup = (gridDim.x >> 3) * 4;
  const int wid = (blockIdx.x >> 3) * 4 + w;

  const float4 bb = *reinterpret_cast<const float4*>(&b[c0]);

  for (int n0 = wid * NPW; n0 < NN; n0 += wavesPerGroup * NPW) {
    const int n = n0 + nsub;
    if (n < NN) {
      const int beg = rowptr[n];
      const int end = rowptr[n + 1];
      float ax = 0.f, ay = 0.f, az = 0.f, aw = 0.f;
      int e = beg;
      for (; e + 3 < end; e += 4) {
        int ca = col[e], cb = col[e + 1], cc = col[e + 2], cd = col[e + 3];
        float sa = NSRC ? nsv[ca] : 1.0f;
        float sb = NSRC ? nsv[cb] : 1.0f;
        float sc = NSRC ? nsv[cc] : 1.0f;
        float sd = NSRC ? nsv[cd] : 1.0f;
        float4 va = *reinterpret_cast<const float4*>(&x[(size_t)ca * D + c0]);
        float4 vb = *reinterpret_cast<const float4*>(&x[(size_t)cb * D + c0]);
        float4 vc = *reinterpret_cast<const float4*>(&x[(size_t)cc * D + c0]);
        float4 vd = *reinterpret_cast<const float4*>(&x[(size_t)cd * D + c0]);
        if (NSRC) {
          ax = fmaf(sa, va.x, fmaf(sb, vb.x, fmaf(sc, vc.x, fmaf(sd, vd.x, ax))));
          ay = fmaf(sa, va.y, fmaf(sb, vb.y, fmaf(sc, vc.y, fmaf(sd, vd.y, ay))));
          az = fmaf(sa, va.z, fmaf(sb, vb.z, fmaf(sc, vc.z, fmaf(sd, vd.z, az))));
          aw = fmaf(sa, va.w, fmaf(sb, vb.w, fmaf(sc, vc.w, fmaf(sd, vd.w, aw))));
        } else {
          ax += (va.x + vb.x) + (vc.x + vd.x);
          ay += (va.y + vb.y) + (vc.y + vd.y);
          az += (va.z + vb.z) + (vc.z + vd.z);
          aw += (va.w + vb.w) + (vc.w + vd.w);
        }
      }
      for (; e < end; ++e) {
        int ca = col[e];
        float sa = NSRC ? nsv[ca] : 1.0f;
        float4 va = *reinterpret_cast<const float4*>(&x[(size_t)ca * D + c0]);
        ax = fmaf(sa, va.x, ax);
        ay = fmaf(sa, va.y, ay);
        az = fmaf(sa, va.z, az);
        aw = fmaf(sa, va.w, aw);
      }
      const float s = nd[n];
      float4 r;
      r.x = fmaf(ax, s, bb.x);
      r.y = fmaf(ay, s, bb.y);
      r.z = fmaf(az, s, bb.z);
      r.w = fmaf(aw, s, bb.w);
      if (RELU) {
        r.x = fmaxf(r.x, 0.f);
        r.y = fmaxf(r.y, 0.f);
        r.z = fmaxf(r.z, 0.f);
        r.w = fmaxf(r.w, 0.f);
      }
      *reinterpret_cast<float4*>(&out[(size_t)n * D + c0]) = r;
    }
  }
}

}  // namespace

extern "C" void kernel_launch(void* const* d_in, const int* in_sizes, int n_in,
                              void* d_out, int out_size, void* d_ws, size_t ws_size,
                              hipStream_t stream) {
  const float* h0  = (const float*)d_in[0];
  const int*   src = (const int*)d_in[1];
  const int*   dst = (const int*)d_in[2];
  const float* W0 = (const float*)d_in[3];
  const float* b0 = (const float*)d_in[4];
  const float* W1 = (const float*)d_in[5];
  const float* b1 = (const float*)d_in[6];
  const float* W2 = (const float*)d_in[7];
  const float* b2 = (const float*)d_in[8];
  const float* W3 = (const float*)d_in[9];
  const float* b3 = (const float*)d_in[10];
  float* out = (float*)d_out;

  // workspace layout (256B aligned)
  char* w = (char*)d_ws;
  size_t off = 0;
  auto take = [&](size_t bytes) {
    char* p = w + off;
    off = (off + bytes + 255) & ~size_t(255);
    return p;
  };
  int*   deg_out = (int*)take(NN * 4);   // adjacent: one memset covers both
  int*   deg_in  = (int*)take(NN * 4);
  float* nsrc    = (float*)take(NN * 4);
  float* ndst    = (float*)take(NN * 4);
  int*   rowptr  = (int*)take((NN + 1) * 4);
  int*   le      = (int*)take(NE * 4);
  int*   col     = (int*)take(NE * 4);
  int*   bsum    = (int*)take(NBLK * 4);
  int*   bpre    = (int*)take(NBLK * 4);
  float* xbuf    = (float*)take((size_t)NN * 128 * 4);
  float* hbuf    = (float*)take((size_t)NN * 128 * 4);
  (void)ws_size; (void)in_sizes; (void)n_in; (void)out_size;

  // zero both degree arrays (contiguous)
  hipMemsetAsync(deg_out, 0, (size_t)((char*)nsrc - (char*)deg_out), stream);

  const int EB = (NE + 255) / 256;
  const int NB = (NN + 255) / 256;

  // fused: degree atomics (blocks 0..255) + layer-0 GEMM x0 = h0@W0 (rest)
  gemm0_deg_kernel<<<DEG_BLOCKS + GEMM_TILES, 256, 0, stream>>>(
      h0, W0, xbuf, src, dst, deg_out, deg_in, le);
  norm_kernel<<<NB, 256, 0, stream>>>(deg_out, deg_in, nsrc, ndst);
  scan_phase1<<<NBLK, SCAN_BLK, 0, stream>>>(deg_in, bsum);
  scan_phase2<<<1, 256, 0, stream>>>(bsum, bpre, rowptr);
  scan_phase3<<<NBLK, SCAN_BLK, 0, stream>>>(deg_in, bpre, rowptr);
  scatter_kernel<<<EB, 256, 0, stream>>>(src, dst, le, rowptr, col);

  const int GATHER_BLOCKS = 2048;  // 8 groups x 256 blocks; group = blockIdx&7

  // layer 0: x0 unscaled -> gather applies ns[col] inside the sum
  gather_kernel<128, true, true><<<GATHER_BLOCKS, 256, 0, stream>>>(
      xbuf, rowptr, col, ndst, b0, nsrc, hbuf);
  // layer 1
  gemm_ns<128><<<GEMM_TILES, 256, 0, stream>>>(hbuf, W1, nsrc, xbuf);
  gather_kernel<128, true, false><<<GATHER_BLOCKS, 256, 0, stream>>>(
      xbuf, rowptr, col, ndst, b1, nullptr, hbuf);
  // layer 2
  gemm_ns<128><<<GEMM_TILES, 256, 0, stream>>>(hbuf, W2, nsrc, xbuf);
  gather_kernel<128, true, false><<<GATHER_BLOCKS, 256, 0, stream>>>(
      xbuf, rowptr, col, ndst, b2, nullptr, hbuf);
  // layer 3: no relu, D=64, straight to d_out
  gemm_ns<64><<<GEMM_TILES, 256, 0, stream>>>(hbuf, W3, nsrc, xbuf);
  gather_kernel<64, false, false><<<GATHER_BLOCKS, 256, 0, stream>>>(
      xbuf, rowptr, col, ndst, b3, nullptr, out);
}